// Round 4
// baseline (141.282 us; speedup 1.0000x reference)
//
#include <hip/hip_runtime.h>

typedef __bf16 bf16;
typedef __bf16 bf16x4 __attribute__((ext_vector_type(4), aligned(8)));
typedef __bf16 bf16x8 __attribute__((ext_vector_type(8), aligned(16)));
typedef float  f32x4  __attribute__((ext_vector_type(4)));

#define B_ 8
#define T_ 16
#define N_ 2048
#define C_ 512

// ---- helpers ----
__device__ inline bf16x8 load8_f32(const float* p) {
    float4 a = *(const float4*)p;
    float4 b = *(const float4*)(p + 4);
    bf16x8 r;
    r[0] = (bf16)a.x; r[1] = (bf16)a.y; r[2] = (bf16)a.z; r[3] = (bf16)a.w;
    r[4] = (bf16)b.x; r[5] = (bf16)b.y; r[6] = (bf16)b.z; r[7] = (bf16)b.w;
    return r;
}

__device__ inline void gload_lds16(const bf16* g, bf16* l) {
    __builtin_amdgcn_global_load_lds(
        (const __attribute__((address_space(1))) void*)g,
        (__attribute__((address_space(3))) void*)l, 16, 0, 0);
}

// One merged prep kernel:
//   blocks [0,2048):    nodes fp32 -> bf16
//   blocks [2048,2064): out_scene = mean_t vd_s
//   blocks [2064,2320): W1t = W1^T (bf16)
//   blocks [2320,2576): W2t = W2^T (bf16)
//   blocks [2576,2592): q[c] += sum_{k in chunk} b1[k]*W2[k][c]  (q pre-zeroed)
__global__ __launch_bounds__(256) void k_prep(
    const float* __restrict__ vd_s, const float* __restrict__ nodes,
    const float* __restrict__ W1, const float* __restrict__ W2,
    const float* __restrict__ b1,
    float* __restrict__ out, bf16* __restrict__ nodes_bf,
    bf16* __restrict__ W1t, bf16* __restrict__ W2t, float* __restrict__ q) {
    __shared__ float sh[32 * 33];
    const int bx = blockIdx.x, tid = threadIdx.x;
    if (bx < 2048) {
        size_t i = ((size_t)bx * 256 + tid) * 16;
        *(bf16x8*)(nodes_bf + i)     = load8_f32(nodes + i);
        *(bf16x8*)(nodes_bf + i + 8) = load8_f32(nodes + i + 8);
    } else if (bx < 2064) {
        int gt = (bx - 2048) * 256 + tid;
        int b = gt >> 9, c = gt & 511;
        float s = 0.f;
#pragma unroll
        for (int t = 0; t < T_; ++t) s += vd_s[(size_t)b * T_ * C_ + t * C_ + c];
        out[b * 2 * C_ + c] = s * (1.0f / T_);
    } else if (bx < 2576) {
        const float* W = (bx < 2320) ? W1 : W2;
        bf16* Wt = (bx < 2320) ? W1t : W2t;
        int idx = (bx < 2320) ? bx - 2064 : bx - 2320;
        int bxx = (idx & 15) * 32, byy = (idx >> 4) * 32;
        int tx = tid & 31, ty = tid >> 5;
#pragma unroll
        for (int r = 0; r < 32; r += 8)
            sh[(ty + r) * 33 + tx] = W[(size_t)(byy + ty + r) * C_ + bxx + tx];
        __syncthreads();
#pragma unroll
        for (int r = 0; r < 32; r += 8)
            Wt[(size_t)(bxx + ty + r) * C_ + byy + tx] = (bf16)sh[tx * 33 + ty + r];
    } else {
        int j = bx - 2576;              // k-chunk [j*32, j*32+32)
#pragma unroll
        for (int h = 0; h < 2; ++h) {
            int c = h * 256 + tid;
            float s = 0.f;
#pragma unroll
            for (int kk = 0; kk < 32; ++kk) {
                int k = j * 32 + kk;
                s += b1[k] * W2[(size_t)k * C_ + c];
            }
            atomicAdd(&q[c], s);
        }
    }
}

// Batched NT GEMM, all bf16: C[z][m][n] = op(sum_k A[z][m][k]*B[z][n][k] + bias[n]).
// op = exp(min(.,30)) if EXPOUT. 128x128 tile, BK=64, global_load_lds staging,
// XOR-swizzled LDS, LDS-transposed vectorized C-write.
template <bool EXPOUT>
__global__ __launch_bounds__(256) void gemm_nt(
    const bf16* __restrict__ A, size_t strideA,
    const bf16* __restrict__ Bm, size_t strideB,
    const float* __restrict__ bias,
    bf16* __restrict__ C, size_t strideC,
    int N, int K) {
    __shared__ __attribute__((aligned(16))) bf16 ls[16896];   // 33792 B
    bf16* lA = ls;            // [128*64]
    bf16* lB = ls + 8192;     // [128*64]
    const int tid = threadIdx.x;
    const int lane = tid & 63, w = tid >> 6;
    const int wm = w >> 1, wn = w & 1;
    const int z = blockIdx.z;
    const int bm = blockIdx.x * 128, bn = blockIdx.y * 128;
    const bf16* Ab = A + (size_t)z * strideA;
    const bf16* Bb = Bm + (size_t)z * strideB;

    f32x4 acc[4][4];
#pragma unroll
    for (int i = 0; i < 4; ++i)
#pragma unroll
        for (int j = 0; j < 4; ++j) acc[i][j] = f32x4{0.f, 0.f, 0.f, 0.f};

    const int nkt = K >> 6;
    for (int kt = 0; kt < nkt; ++kt) {
        // stage 128x64 A and B tiles; linear LDS dest + inverse-swizzled global src
#pragma unroll
        for (int c = 0; c < 4; ++c) {
            int ca = c * 256 + tid;
            int row = ca >> 3;
            int qd = (ca & 7) ^ (row & 7);
            gload_lds16(Ab + (size_t)(bm + row) * K + kt * 64 + qd * 8,
                        lA + c * 2048 + w * 512);
            gload_lds16(Bb + (size_t)(bn + row) * K + kt * 64 + qd * 8,
                        lB + c * 2048 + w * 512);
        }
        __syncthreads();

        bf16x8 af[2][4], bfr[2][4];
#pragma unroll
        for (int ks = 0; ks < 2; ++ks) {
            int y = ks * 4 + (lane >> 4);
#pragma unroll
            for (int i = 0; i < 4; ++i) {
                int ra = wm * 64 + i * 16 + (lane & 15);
                int rb = wn * 64 + i * 16 + (lane & 15);
                af[ks][i]  = *(const bf16x8*)&lA[ra * 64 + ((y ^ (ra & 7)) * 8)];
                bfr[ks][i] = *(const bf16x8*)&lB[rb * 64 + ((y ^ (rb & 7)) * 8)];
            }
        }
#pragma unroll
        for (int ks = 0; ks < 2; ++ks)
#pragma unroll
            for (int i = 0; i < 4; ++i)
#pragma unroll
                for (int j = 0; j < 4; ++j)
                    acc[i][j] = __builtin_amdgcn_mfma_f32_16x16x32_bf16(
                        af[ks][i], bfr[j >= 0 ? ks : 0][j], acc[i][j], 0, 0, 0);
        __syncthreads();
    }

    // ---- epilogue: stage 128x128 bf16 tile in LDS (stride 132), vector store ----
    bf16* Cb = C + (size_t)z * strideC;
#pragma unroll
    for (int i = 0; i < 4; ++i) {
#pragma unroll
        for (int j = 0; j < 4; ++j) {
            int coll = wn * 64 + j * 16 + (lane & 15);
            float bv = bias ? bias[bn + coll] : 0.f;
#pragma unroll
            for (int r = 0; r < 4; ++r) {
                int rowl = wm * 64 + i * 16 + (lane >> 4) * 4 + r;
                float v = acc[i][j][r] + bv;
                if (EXPOUT) v = __expf(fminf(v, 30.f));
                ls[rowl * 132 + coll] = (bf16)v;
            }
        }
    }
    __syncthreads();
#pragma unroll
    for (int it = 0; it < 8; ++it) {
        int rowl = it * 16 + (tid >> 4);
        int c0 = (tid & 15) * 8;
        bf16x4 lo = *(const bf16x4*)&ls[rowl * 132 + c0];
        bf16x4 hi = *(const bf16x4*)&ls[rowl * 132 + c0 + 4];
        bf16x8 vv = __builtin_shufflevector(lo, hi, 0, 1, 2, 3, 4, 5, 6, 7);
        *(bf16x8*)(Cb + (size_t)(bm + rowl) * N + bn + c0) = vv;
    }
}

// P is exp(adj) unnormalized. Per 16-row strip: l_i = row sums, then
// w[j] += sum_i P[i][j]/l_i  (fp32 atomics).
__global__ __launch_bounds__(256) void k_w(const bf16* __restrict__ P,
                                           float* __restrict__ w) {
    __shared__ __attribute__((aligned(16))) bf16 strip[16 * 2048];   // 64KB
    __shared__ float rinv_s[16];
    const int tid = threadIdx.x;
    const int b = blockIdx.y, rb = blockIdx.x;
    const bf16* src = P + (size_t)b * N_ * N_ + (size_t)rb * 16 * N_;
#pragma unroll
    for (int i = 0; i < 16; ++i) {
        int c = i * 256 + tid;
        ((bf16x8*)strip)[c] = ((const bf16x8*)src)[c];
    }
    __syncthreads();
    const int row = tid >> 4, s = tid & 15;
    float l = 0.f;
#pragma unroll
    for (int i = 0; i < 16; ++i) {
        bf16x8 rv = *(const bf16x8*)&strip[row * 2048 + (s + 16 * i) * 8];
#pragma unroll
        for (int e = 0; e < 8; ++e) l += (float)rv[e];
    }
#pragma unroll
    for (int msk = 8; msk; msk >>= 1) l += __shfl_xor(l, msk);
    if (s == 0) rinv_s[row] = 1.0f / l;
    __syncthreads();
    float ri[16];
#pragma unroll
    for (int r = 0; r < 16; ++r) ri[r] = rinv_s[r];
    float* wb = w + b * N_;
#pragma unroll
    for (int jc = 0; jc < 8; ++jc) {
        int j = jc * 256 + tid;
        float sum = 0.f;
#pragma unroll
        for (int r = 0; r < 16; ++r) sum += ri[r] * (float)strip[r * 2048 + j];
        atomicAdd(&wb[j], sum);
    }
}

// gpacc[b][c] += sum_{j in slab} (w[b][j]+1) * nodes_bf[b][j][c]
// grid (16 slabs, 8 b); 256 threads: 64 col-chunks x 4 j-rows.
__global__ void k_gp(const bf16* __restrict__ nodes_bf, const float* __restrict__ w,
                     float* __restrict__ gpacc) {
    const int tid = threadIdx.x;
    const int b = blockIdx.y;
    const int j0 = blockIdx.x * 128;
    const int cc = (tid & 63) * 8, jr = tid >> 6;
    const bf16* nb = nodes_bf + (size_t)b * N_ * C_;
    const float* wb = w + b * N_;
    float acc8[8] = {0.f, 0.f, 0.f, 0.f, 0.f, 0.f, 0.f, 0.f};
    for (int j = jr; j < 128; j += 4) {
        float wj = wb[j0 + j] + 1.0f;
        bf16x8 nv = *(const bf16x8*)&nb[(size_t)(j0 + j) * C_ + cc];
#pragma unroll
        for (int e = 0; e < 8; ++e) acc8[e] += wj * (float)nv[e];
    }
#pragma unroll
    for (int e = 0; e < 8; ++e) atomicAdd(&gpacc[b * C_ + cc + e], acc8[e]);
}

__global__ void k_fin(const float* __restrict__ gpacc, float* __restrict__ out) {
    int gt = blockIdx.x * 256 + threadIdx.x;
    int b = gt >> 9, c = gt & 511;
    out[b * 2 * C_ + C_ + c] = gpacc[b * C_ + c] * (1.0f / N_);
}

extern "C" void kernel_launch(void* const* d_in, const int* in_sizes, int n_in,
                              void* d_out, int out_size, void* d_ws, size_t ws_size,
                              hipStream_t stream) {
    const float* vd_s  = (const float*)d_in[0];
    const float* nodes = (const float*)d_in[1];
    const float* W1    = (const float*)d_in[2];
    const float* b1    = (const float*)d_in[3];
    const float* W2    = (const float*)d_in[4];
    // d_in[5] (b2) adds a row-constant to adj -> cancels in row-softmax -> unused
    float* out = (float*)d_out;

    char* ws = (char*)d_ws;
    bf16*  nodes_bf = (bf16*)(ws);                                   // 16 MB
    bf16*  H2       = (bf16*)(ws + ((size_t)16 << 20));              // 16 MB
    bf16*  P        = (bf16*)(ws + ((size_t)32 << 20));              // 64 MB
    bf16*  W1t      = (bf16*)(ws + ((size_t)96 << 20));              // 512 KB
    bf16*  W2t      = (bf16*)(ws + ((size_t)96 << 20) + (512u << 10));
    bf16*  Gt       = (bf16*)(ws + ((size_t)96 << 20) + (1024u << 10));
    float* q        = (float*)(ws + ((size_t)96 << 20) + (1536u << 10));  // 4 KB slot
    float* w        = (float*)(ws + ((size_t)96 << 20) + (1536u << 10) + 4096);
    float* gpacc    = (float*)(ws + ((size_t)96 << 20) + (1536u << 10) + 4096 + 65536);

    // zero q + w + gpacc (contiguous 86016 B)
    (void)hipMemsetAsync(q, 0, 4096 + 65536 + 16384, stream);

    k_prep<<<2592, 256, 0, stream>>>(vd_s, nodes, W1, W2, b1,
                                     out, nodes_bf, W1t, W2t, q);

    // Gt[c][k] = sum_m W2t[c][m]*W1t[k][m]   (M=N=K=512)
    gemm_nt<false><<<dim3(4, 4, 1), 256, 0, stream>>>(
        W2t, 0, W1t, 0, nullptr, Gt, 0, C_, C_);
    // H2[b] = nodes_bf[b] @ Gt^T + q[col]   (M=2048, N=512, K=512)
    gemm_nt<false><<<dim3(16, 4, 8), 256, 0, stream>>>(
        nodes_bf, (size_t)N_ * C_, Gt, 0, q,
        H2, (size_t)N_ * C_, C_, C_);
    // P[b] = exp(H2[b] @ nodes_bf[b]^T)   (M=2048, N=2048, K=512)
    gemm_nt<true><<<dim3(16, 16, 8), 256, 0, stream>>>(
        H2, (size_t)N_ * C_, nodes_bf, (size_t)N_ * C_, nullptr,
        P, (size_t)N_ * N_, N_, C_);

    k_w<<<dim3(128, 8), 256, 0, stream>>>(P, w);
    k_gp<<<dim3(16, 8), 256, 0, stream>>>(nodes_bf, w, gpacc);
    k_fin<<<16, 256, 0, stream>>>(gpacc, out);
}

// Round 5
// 140.398 us; speedup vs baseline: 1.0063x; 1.0063x over previous
//
#include <hip/hip_runtime.h>

typedef __bf16 bf16;
typedef __bf16 bf16x8 __attribute__((ext_vector_type(8), aligned(16)));
typedef float  f32x4  __attribute__((ext_vector_type(4)));

#define B_ 8
#define T_ 16
#define N_ 2048
#define C_ 512

// ---- helpers ----
__device__ inline bf16x8 load8_f32(const float* p) {
    float4 a = *(const float4*)p;
    float4 b = *(const float4*)(p + 4);
    bf16x8 r;
    r[0] = (bf16)a.x; r[1] = (bf16)a.y; r[2] = (bf16)a.z; r[3] = (bf16)a.w;
    r[4] = (bf16)b.x; r[5] = (bf16)b.y; r[6] = (bf16)b.z; r[7] = (bf16)b.w;
    return r;
}

__device__ inline void gload_lds16(const bf16* g, bf16* l) {
    __builtin_amdgcn_global_load_lds(
        (const __attribute__((address_space(1))) void*)g,
        (__attribute__((address_space(3))) void*)l, 16, 0, 0);
}

// One merged prep kernel:
//   blocks [0,2048):    nodes fp32 -> bf16
//   blocks [2048,2064): out_scene = mean_t vd_s
//   blocks [2064,2320): W1t = W1^T (bf16)
//   blocks [2320,2576): W2t = W2^T (bf16)
//   blocks [2576,2592): q[c] += sum_{k in chunk} b1[k]*W2[k][c]  (q pre-zeroed)
__global__ __launch_bounds__(256) void k_prep(
    const float* __restrict__ vd_s, const float* __restrict__ nodes,
    const float* __restrict__ W1, const float* __restrict__ W2,
    const float* __restrict__ b1,
    float* __restrict__ out, bf16* __restrict__ nodes_bf,
    bf16* __restrict__ W1t, bf16* __restrict__ W2t, float* __restrict__ q) {
    __shared__ float sh[32 * 33];
    const int bx = blockIdx.x, tid = threadIdx.x;
    if (bx < 2048) {
        size_t i = ((size_t)bx * 256 + tid) * 16;
        *(bf16x8*)(nodes_bf + i)     = load8_f32(nodes + i);
        *(bf16x8*)(nodes_bf + i + 8) = load8_f32(nodes + i + 8);
    } else if (bx < 2064) {
        int gt = (bx - 2048) * 256 + tid;
        int b = gt >> 9, c = gt & 511;
        float s = 0.f;
#pragma unroll
        for (int t = 0; t < T_; ++t) s += vd_s[(size_t)b * T_ * C_ + t * C_ + c];
        out[b * 2 * C_ + c] = s * (1.0f / T_);
    } else if (bx < 2576) {
        const float* W = (bx < 2320) ? W1 : W2;
        bf16* Wt = (bx < 2320) ? W1t : W2t;
        int idx = (bx < 2320) ? bx - 2064 : bx - 2320;
        int bxx = (idx & 15) * 32, byy = (idx >> 4) * 32;
        int tx = tid & 31, ty = tid >> 5;
#pragma unroll
        for (int r = 0; r < 32; r += 8)
            sh[(ty + r) * 33 + tx] = W[(size_t)(byy + ty + r) * C_ + bxx + tx];
        __syncthreads();
#pragma unroll
        for (int r = 0; r < 32; r += 8)
            Wt[(size_t)(bxx + ty + r) * C_ + byy + tx] = (bf16)sh[tx * 33 + ty + r];
    } else {
        int j = bx - 2576;
#pragma unroll
        for (int h = 0; h < 2; ++h) {
            int c = h * 256 + tid;
            float s = 0.f;
#pragma unroll
            for (int kk = 0; kk < 32; ++kk) {
                int k = j * 32 + kk;
                s += b1[k] * W2[(size_t)k * C_ + c];
            }
            atomicAdd(&q[c], s);
        }
    }
}

// 128x128-tile NT GEMM (round-3 structure): C = A*B^T + bias.  Used for Gt, H2.
__global__ __launch_bounds__(256) void gemm_nt(
    const bf16* __restrict__ A, size_t strideA,
    const bf16* __restrict__ Bm, size_t strideB,
    const float* __restrict__ bias,
    bf16* __restrict__ C, size_t strideC,
    int N, int K) {
    __shared__ __attribute__((aligned(16))) bf16 lA[128 * 64];
    __shared__ __attribute__((aligned(16))) bf16 lB[128 * 64];
    const int tid = threadIdx.x;
    const int lane = tid & 63, w = tid >> 6;
    const int wm = w >> 1, wn = w & 1;
    const int z = blockIdx.z;
    const int bm = blockIdx.x * 128, bn = blockIdx.y * 128;
    const bf16* Ab = A + (size_t)z * strideA;
    const bf16* Bb = Bm + (size_t)z * strideB;

    f32x4 acc[4][4];
#pragma unroll
    for (int i = 0; i < 4; ++i)
#pragma unroll
        for (int j = 0; j < 4; ++j) acc[i][j] = f32x4{0.f, 0.f, 0.f, 0.f};

    const int nkt = K >> 6;
    for (int kt = 0; kt < nkt; ++kt) {
#pragma unroll
        for (int c = 0; c < 4; ++c) {
            int ca = c * 256 + tid;
            int row = ca >> 3;
            int qd = (ca & 7) ^ (row & 7);
            gload_lds16(Ab + (size_t)(bm + row) * K + kt * 64 + qd * 8,
                        lA + c * 2048 + w * 512);
            gload_lds16(Bb + (size_t)(bn + row) * K + kt * 64 + qd * 8,
                        lB + c * 2048 + w * 512);
        }
        __syncthreads();

        bf16x8 af[2][4], bfr[2][4];
#pragma unroll
        for (int ks = 0; ks < 2; ++ks) {
            int y = ks * 4 + (lane >> 4);
#pragma unroll
            for (int i = 0; i < 4; ++i) {
                int ra = wm * 64 + i * 16 + (lane & 15);
                int rb = wn * 64 + i * 16 + (lane & 15);
                af[ks][i]  = *(const bf16x8*)&lA[ra * 64 + ((y ^ (ra & 7)) * 8)];
                bfr[ks][i] = *(const bf16x8*)&lB[rb * 64 + ((y ^ (rb & 7)) * 8)];
            }
        }
#pragma unroll
        for (int ks = 0; ks < 2; ++ks)
#pragma unroll
            for (int i = 0; i < 4; ++i)
#pragma unroll
                for (int j = 0; j < 4; ++j)
                    acc[i][j] = __builtin_amdgcn_mfma_f32_16x16x32_bf16(
                        af[ks][i], bfr[ks][j], acc[i][j], 0, 0, 0);
        __syncthreads();
    }

    bf16* Cb = C + (size_t)z * strideC;
#pragma unroll
    for (int i = 0; i < 4; ++i) {
#pragma unroll
        for (int j = 0; j < 4; ++j) {
            int col = bn + wn * 64 + j * 16 + (lane & 15);
            float bv = bias ? bias[col] : 0.f;
#pragma unroll
            for (int r = 0; r < 4; ++r) {
                int row = bm + wm * 64 + i * 16 + (lane >> 4) * 4 + r;
                Cb[(size_t)row * N + col] = (bf16)(acc[i][j][r] + bv);
            }
        }
    }
}

// 256x256-tile 8-phase NT GEMM (T2+T3+T4+T5), fixed geometry:
// M=N=2048 per batch, 8 batches, K=512. grid = 512 blocks x 512 threads.
// C[z][m][n] = op(sum_k A[z][m][k]*B[z][n][k]), op=exp if EXPOUT.
template <bool EXPOUT>
__global__ __launch_bounds__(512, 2) void gemm256(
    const bf16* __restrict__ A, size_t strideA,
    const bf16* __restrict__ Bm, size_t strideB,
    bf16* __restrict__ C, size_t strideC,
    int N, int K) {
    __shared__ __attribute__((aligned(16))) bf16 ls[2][2][16384];   // 128 KiB
    const int tid = threadIdx.x;
    const int lane = tid & 63, w = tid >> 6;
    const int wm = w >> 2, wn = w & 3;            // 2 x 4 wave grid
    // XCD swizzle: 512 blocks, id%8 = XCD -> batch z == XCD, tiles contiguous.
    int id = blockIdx.x;
    int sw = (id & 7) * 64 + (id >> 3);
    const int z = sw >> 6, t = sw & 63;
    const int bm = (t >> 3) * 256, bn = (t & 7) * 256;
    const bf16* Ab = A + (size_t)z * strideA;
    const bf16* Bb = Bm + (size_t)z * strideB;

    f32x4 acc[8][4];
#pragma unroll
    for (int i = 0; i < 8; ++i)
#pragma unroll
        for (int j = 0; j < 4; ++j) acc[i][j] = f32x4{0.f, 0.f, 0.f, 0.f};

    const int nkt = K >> 6;                        // 8

#define STAGE256(kt_, bufi)                                                       \
    {                                                                             \
        bf16* sA = &ls[bufi][0][0] + w * 512;                                     \
        bf16* sB = &ls[bufi][1][0] + w * 512;                                     \
        _Pragma("unroll")                                                         \
        for (int l = 0; l < 4; ++l) {                                             \
            int p = l * 512 + tid;                                                \
            int row = p >> 3;                                                     \
            int qd = (p & 7) ^ (row & 7);                                         \
            gload_lds16(Ab + (size_t)(bm + row) * K + (kt_) * 64 + qd * 8,        \
                        sA + l * 4096);                                           \
            gload_lds16(Bb + (size_t)(bn + row) * K + (kt_) * 64 + qd * 8,        \
                        sB + l * 4096);                                           \
        }                                                                         \
    }

    // prologue: tile0 -> buf0, tile1 -> buf1 (16 loads in flight)
    STAGE256(0, 0);
    STAGE256(1, 1);

    for (int kt = 0; kt < nkt; ++kt) {
        const int cur = kt & 1;
        const bf16* lA = &ls[cur][0][0];
        const bf16* lB = &ls[cur][1][0];
        // wait this tile's 8 loads; keep next tile's 8 in flight (counted vmcnt)
        if (kt + 1 < nkt) asm volatile("s_waitcnt vmcnt(8)" ::: "memory");
        else              asm volatile("s_waitcnt vmcnt(0)" ::: "memory");
        __builtin_amdgcn_s_barrier();              // all waves' loads landed
        asm volatile("" ::: "memory");
#pragma unroll
        for (int ph = 0; ph < 4; ++ph) {           // quadrant: rows a*64, cols bq*32
            const int a = ph >> 1, bq = ph & 1;
            bf16x8 af[4][2], bfv[2][2];
#pragma unroll
            for (int i = 0; i < 4; ++i) {
                int ra = wm * 128 + a * 64 + i * 16 + (lane & 15);
#pragma unroll
                for (int ks = 0; ks < 2; ++ks) {
                    int y = ks * 4 + (lane >> 4);
                    af[i][ks] = *(const bf16x8*)&lA[ra * 64 + ((y ^ (ra & 7)) * 8)];
                }
            }
#pragma unroll
            for (int j = 0; j < 2; ++j) {
                int rb = wn * 64 + bq * 32 + j * 16 + (lane & 15);
#pragma unroll
                for (int ks = 0; ks < 2; ++ks) {
                    int y = ks * 4 + (lane >> 4);
                    bfv[j][ks] = *(const bf16x8*)&lB[rb * 64 + ((y ^ (rb & 7)) * 8)];
                }
            }
            __builtin_amdgcn_s_barrier();          // align issue across waves
            asm volatile("s_waitcnt lgkmcnt(0)" ::: "memory");
            __builtin_amdgcn_s_setprio(1);
#pragma unroll
            for (int ks = 0; ks < 2; ++ks)
#pragma unroll
                for (int i = 0; i < 4; ++i)
#pragma unroll
                    for (int j = 0; j < 2; ++j)
                        acc[a * 4 + i][bq * 2 + j] =
                            __builtin_amdgcn_mfma_f32_16x16x32_bf16(
                                af[i][ks], bfv[j][ks], acc[a * 4 + i][bq * 2 + j],
                                0, 0, 0);
            __builtin_amdgcn_s_setprio(0);
            __builtin_amdgcn_s_barrier();          // phase done (collective)
        }
        // buf[cur] fully consumed by ALL waves -> restage it for tile kt+2
        asm volatile("" ::: "memory");
        if (kt + 2 < nkt) STAGE256(kt + 2, cur);
    }

    bf16* Cb = C + (size_t)z * strideC;
#pragma unroll
    for (int fi = 0; fi < 8; ++fi) {
#pragma unroll
        for (int fj = 0; fj < 4; ++fj) {
            int roff = (fi >> 2) * 64 + (fi & 3) * 16;
            int coff = (fj >> 1) * 32 + (fj & 1) * 16;
            int col = bn + wn * 64 + coff + (lane & 15);
#pragma unroll
            for (int r = 0; r < 4; ++r) {
                int row = bm + wm * 128 + roff + (lane >> 4) * 4 + r;
                float v = acc[fi][fj][r];
                if (EXPOUT) v = __expf(fminf(v, 30.f));
                Cb[(size_t)row * N + col] = (bf16)v;
            }
        }
    }
#undef STAGE256
}

// P is exp(adj) unnormalized. Per 16-row strip: l_i = row sums, then
// w[j] += sum_i P[i][j]/l_i  (fp32 atomics).
__global__ __launch_bounds__(256) void k_w(const bf16* __restrict__ P,
                                           float* __restrict__ w) {
    __shared__ __attribute__((aligned(16))) bf16 strip[16 * 2048];   // 64KB
    __shared__ float rinv_s[16];
    const int tid = threadIdx.x;
    const int b = blockIdx.y, rb = blockIdx.x;
    const bf16* src = P + (size_t)b * N_ * N_ + (size_t)rb * 16 * N_;
#pragma unroll
    for (int i = 0; i < 16; ++i) {
        int c = i * 256 + tid;
        ((bf16x8*)strip)[c] = ((const bf16x8*)src)[c];
    }
    __syncthreads();
    const int row = tid >> 4, s = tid & 15;
    float l = 0.f;
#pragma unroll
    for (int i = 0; i < 16; ++i) {
        bf16x8 rv = *(const bf16x8*)&strip[row * 2048 + (s + 16 * i) * 8];
#pragma unroll
        for (int e = 0; e < 8; ++e) l += (float)rv[e];
    }
#pragma unroll
    for (int msk = 8; msk; msk >>= 1) l += __shfl_xor(l, msk);
    if (s == 0) rinv_s[row] = 1.0f / l;
    __syncthreads();
    float ri[16];
#pragma unroll
    for (int r = 0; r < 16; ++r) ri[r] = rinv_s[r];
    float* wb = w + b * N_;
#pragma unroll
    for (int jc = 0; jc < 8; ++jc) {
        int j = jc * 256 + tid;
        float sum = 0.f;
#pragma unroll
        for (int r = 0; r < 16; ++r) sum += ri[r] * (float)strip[r * 2048 + j];
        atomicAdd(&wb[j], sum);
    }
}

// gpacc[b][c] += sum_{j in slab} (w[b][j]+1) * nodes_bf[b][j][c]
__global__ void k_gp(const bf16* __restrict__ nodes_bf, const float* __restrict__ w,
                     float* __restrict__ gpacc) {
    const int tid = threadIdx.x;
    const int b = blockIdx.y;
    const int j0 = blockIdx.x * 128;
    const int cc = (tid & 63) * 8, jr = tid >> 6;
    const bf16* nb = nodes_bf + (size_t)b * N_ * C_;
    const float* wb = w + b * N_;
    float acc8[8] = {0.f, 0.f, 0.f, 0.f, 0.f, 0.f, 0.f, 0.f};
    for (int j = jr; j < 128; j += 4) {
        float wj = wb[j0 + j] + 1.0f;
        bf16x8 nv = *(const bf16x8*)&nb[(size_t)(j0 + j) * C_ + cc];
#pragma unroll
        for (int e = 0; e < 8; ++e) acc8[e] += wj * (float)nv[e];
    }
#pragma unroll
    for (int e = 0; e < 8; ++e) atomicAdd(&gpacc[b * C_ + cc + e], acc8[e]);
}

__global__ void k_fin(const float* __restrict__ gpacc, float* __restrict__ out) {
    int gt = blockIdx.x * 256 + threadIdx.x;
    int b = gt >> 9, c = gt & 511;
    out[b * 2 * C_ + C_ + c] = gpacc[b * C_ + c] * (1.0f / N_);
}

extern "C" void kernel_launch(void* const* d_in, const int* in_sizes, int n_in,
                              void* d_out, int out_size, void* d_ws, size_t ws_size,
                              hipStream_t stream) {
    const float* vd_s  = (const float*)d_in[0];
    const float* nodes = (const float*)d_in[1];
    const float* W1    = (const float*)d_in[2];
    const float* b1    = (const float*)d_in[3];
    const float* W2    = (const float*)d_in[4];
    // d_in[5] (b2) adds a row-constant to adj -> cancels in row-softmax -> unused
    float* out = (float*)d_out;

    char* ws = (char*)d_ws;
    bf16*  nodes_bf = (bf16*)(ws);                                   // 16 MB
    bf16*  H2       = (bf16*)(ws + ((size_t)16 << 20));              // 16 MB
    bf16*  P        = (bf16*)(ws + ((size_t)32 << 20));              // 64 MB
    bf16*  W1t      = (bf16*)(ws + ((size_t)96 << 20));              // 512 KB
    bf16*  W2t      = (bf16*)(ws + ((size_t)96 << 20) + (512u << 10));
    bf16*  Gt       = (bf16*)(ws + ((size_t)96 << 20) + (1024u << 10));
    float* q        = (float*)(ws + ((size_t)96 << 20) + (1536u << 10));  // 4 KB slot
    float* w        = (float*)(ws + ((size_t)96 << 20) + (1536u << 10) + 4096);
    float* gpacc    = (float*)(ws + ((size_t)96 << 20) + (1536u << 10) + 4096 + 65536);

    // zero q + w + gpacc (contiguous 86016 B)
    (void)hipMemsetAsync(q, 0, 4096 + 65536 + 16384, stream);

    k_prep<<<2592, 256, 0, stream>>>(vd_s, nodes, W1, W2, b1,
                                     out, nodes_bf, W1t, W2t, q);

    // Gt[c][k] = sum_m W2t[c][m]*W1t[k][m]   (M=N=K=512)
    gemm_nt<<<dim3(4, 4, 1), 256, 0, stream>>>(
        W2t, 0, W1t, 0, nullptr, Gt, 0, C_, C_);
    // H2[b] = nodes_bf[b] @ Gt^T + q[col]   (M=2048, N=512, K=512)
    gemm_nt<<<dim3(16, 4, 8), 256, 0, stream>>>(
        nodes_bf, (size_t)N_ * C_, Gt, 0, q,
        H2, (size_t)N_ * C_, C_, C_);
    // P[b] = exp(H2[b] @ nodes_bf[b]^T)   (M=2048, N=2048, K=512), 8-phase 256^2
    gemm256<true><<<512, 512, 0, stream>>>(
        H2, (size_t)N_ * C_, nodes_bf, (size_t)N_ * C_,
        P, (size_t)N_ * N_, N_, C_);

    k_w<<<dim3(128, 8), 256, 0, stream>>>(P, w);
    k_gp<<<dim3(16, 8), 256, 0, stream>>>(nodes_bf, w, gpacc);
    k_fin<<<16, 256, 0, stream>>>(gpacc, out);
}